// Round 1
// 319.405 us; speedup vs baseline: 1.0123x; 1.0123x over previous
//
#include <hip/hip_runtime.h>
#include <hip/hip_fp16.h>

// ---------------------------------------------------------------------------
// GATv2 x2 + classifier. N=50000, E=800000, IN=128, HEADS=4, HID=32, OUT=16.
// R11: (a) scatter fused INTO gemm1 dispatch (block-role split 1024:782,
//      interleaved 5:4): scatter is atomic-latency-bound (3% VALU), gemm1 is
//      MFMA-bound -- overlap instead of serialize. Scatter now stages its
//      edge chunk in LDS once and loops the 8 node-slices from LDS (dst read
//      1x instead of 8x).
//      (b) attn inner loop: v_pk_add_f16 + v_fma_mix_f32 (op_sel fp16
//      operands, |abs| folded) -- ~46 -> ~30 VALU insts per edge-body,
//      numerically identical e/acc accumulation in f32.
//      (c) h1 stored as bf16 hi/lo pair (written from attn1's fp32 regs) so
//      gemm2 A-staging is pure uint4 copies (no split VALU) and the h1-fp16
//      rounding error disappears.
//      (d) count_kernel merged into convert_W (independent; one launch less).
// ---------------------------------------------------------------------------

#define LOG2E 1.4426950408889634f
#define AST 40  // LDS row stride in shorts (80B rows; fragment reads 2-way=free)

typedef short bf16x8 __attribute__((ext_vector_type(8)));
typedef float f32x4 __attribute__((ext_vector_type(4)));

__device__ __forceinline__ unsigned short f2bf(float f) {
  union { float f; unsigned u; } x; x.f = f;
  unsigned r = x.u + 0x7fffu + ((x.u >> 16) & 1u);
  return (unsigned short)(r >> 16);
}
__device__ __forceinline__ float bf2f(unsigned short h) {
  union { unsigned u; float f; } x; x.u = ((unsigned)h) << 16;
  return x.f;
}
__device__ __forceinline__ void split4(float4 v, ushort4& h, ushort4& l) {
  h.x = f2bf(v.x); l.x = f2bf(v.x - bf2f(h.x));
  h.y = f2bf(v.y); l.y = f2bf(v.y - bf2f(h.y));
  h.z = f2bf(v.z); l.z = f2bf(v.z - bf2f(h.z));
  h.w = f2bf(v.w); l.w = f2bf(v.w - bf2f(h.w));
}

// ---- v_fma_mix_f32 helpers: d = a * (f16 half of b) + c, all-f32 accum ----
__device__ __forceinline__ float mixlo(float a, unsigned b, float c) {
  float d;
  asm("v_fma_mix_f32 %0, %1, %2, %3 op_sel_hi:[0,1,0]"
      : "=v"(d) : "v"(a), "v"(b), "v"(c));
  return d;
}
__device__ __forceinline__ float mixhi(float a, unsigned b, float c) {
  float d;
  asm("v_fma_mix_f32 %0, %1, %2, %3 op_sel:[0,1,0] op_sel_hi:[0,1,0]"
      : "=v"(d) : "v"(a), "v"(b), "v"(c));
  return d;
}
__device__ __forceinline__ float mixlo_abs(float a, unsigned b, float c) {
  float d;
  asm("v_fma_mix_f32 %0, %1, |%2|, %3 op_sel_hi:[0,1,0]"
      : "=v"(d) : "v"(a), "v"(b), "v"(c));
  return d;
}
__device__ __forceinline__ float mixhi_abs(float a, unsigned b, float c) {
  float d;
  asm("v_fma_mix_f32 %0, %1, |%2|, %3 op_sel:[0,1,0] op_sel_hi:[0,1,0]"
      : "=v"(d) : "v"(a), "v"(b), "v"(c));
  return d;
}
__device__ __forceinline__ unsigned pk_add(unsigned a, unsigned b) {
  union { unsigned u; __half2 h; } x, y, r;
  x.u = a; y.u = b;
  r.h = __hadd2(x.h, y.h);
  return r.u;
}

// ------------------------------ CSR build ----------------------------------

__global__ __launch_bounds__(256) void zero_i32(int* __restrict__ p, int n) {
  int i = blockIdx.x * 256 + threadIdx.x;
  if (i < n) p[i] = 0;
}

// per-block scan of (cnt[i]+1)  (+1 = self loop slot)
__global__ __launch_bounds__(256) void scan_blk(const int* __restrict__ cnt,
                                                int* __restrict__ excl,
                                                int* __restrict__ bsum, int n) {
  __shared__ int s[256];
  int t = threadIdx.x, i = blockIdx.x * 256 + t;
  int v = (i < n) ? (cnt[i] + 1) : 0;
  s[t] = v;
  __syncthreads();
#pragma unroll
  for (int off = 1; off < 256; off <<= 1) {
    int u = (t >= off) ? s[t - off] : 0;
    __syncthreads();
    s[t] += u;
    __syncthreads();
  }
  if (i < n) excl[i] = s[t] - v;
  if (t == 255) bsum[blockIdx.x] = s[255];
}

__global__ __launch_bounds__(256) void scan_bsum(int* __restrict__ bsum, int nb,
                                                 int* __restrict__ row_start, int n) {
  __shared__ int s[256];
  int t = threadIdx.x;
  int v = (t < nb) ? bsum[t] : 0;
  s[t] = v;
  __syncthreads();
#pragma unroll
  for (int off = 1; off < 256; off <<= 1) {
    int u = (t >= off) ? s[t - off] : 0;
    __syncthreads();
    s[t] += u;
    __syncthreads();
  }
  if (t < nb) bsum[t] = s[t] - v;
  if (t == 255) row_start[n] = s[255];
}

// add block offsets; write self-loop entry; wpos starts past it; zero csr pad
__global__ __launch_bounds__(256) void scan_add(int* __restrict__ row_start,
                                                const int* __restrict__ bsum,
                                                int* __restrict__ wpos,
                                                int* __restrict__ csr,
                                                int n, int padBase) {
  int i = blockIdx.x * 256 + threadIdx.x;
  if (i < n) {
    int r = row_start[i] + bsum[blockIdx.x];
    row_start[i] = r;
    wpos[i] = r + 1;
    csr[r] = i;  // self loop first in each row
  }
  if (blockIdx.x == 0 && threadIdx.x < 16) csr[padBase + threadIdx.x] = 0;
}

// --------------------- weight convert + degree count -----------------------
// blocks 0..255: split-bf16 weight transpose (both layers)
// blocks 256.. : edge-degree count (independent work, merged launch)
__global__ __launch_bounds__(256) void convert_count(
    const float* __restrict__ Wl1, const float* __restrict__ Wr1,
    const float* __restrict__ Wl2, const float* __restrict__ Wr2,
    unsigned short* __restrict__ BT1h, unsigned short* __restrict__ BT1l,
    unsigned short* __restrict__ BT2h, unsigned short* __restrict__ BT2l,
    const int* __restrict__ dst, int* __restrict__ cnt, int E) {
  int b = blockIdx.x;
  if (b >= 256) {
    int i = (b - 256) * 256 + threadIdx.x;
    if (i < E) atomicAdd(&cnt[dst[i]], 1);
    return;
  }
  const float* Wl = (b < 128) ? Wl1 : Wl2;
  const float* Wr = (b < 128) ? Wr1 : Wr2;
  unsigned short* BTh = (b < 128) ? BT1h : BT2h;
  unsigned short* BTl = (b < 128) ? BT1l : BT2l;
  int idx = (b & 127) * 256 + threadIdx.x;  // 0..32767
  int col = idx >> 7, k = idx & 127;
  float v = (col < 128) ? Wl[k * 128 + col] : Wr[k * 128 + (col - 128)];
  unsigned short h = f2bf(v);
  BTh[idx] = h;
  BTl[idx] = f2bf(v - bf2f(h));
}

// ------------------------ MFMA GEMM (+fused scatter) -----------------------
// C[N x 256] = A[N x 128] @ W[128 x 256], split-bf16 3-term; C stored fp16.
// Block = 128 rows x 128 cols. 4 waves, each 64x64 (16 acc tiles).
// FUSE=1: grid also carries 1024 scatter blocks (interleaved 5 scatter :
// 4 gemm per group of 9). Scatter stages its edge chunk in LDS once, then
// loops 8 node-slices (phase-aligned across blocks -> csr write locality).
enum { IN_F32 = 0, IN_BFPAIR = 1 };
template <int MODE, int FUSE>
__global__ __launch_bounds__(256) void gemm_mfma(
    const float* __restrict__ Af,
    const unsigned short* __restrict__ Ah, const unsigned short* __restrict__ Al,
    const unsigned short* __restrict__ BTh, const unsigned short* __restrict__ BTl,
    __half* __restrict__ Cl, __half* __restrict__ Cr, int nrows,
    const int* __restrict__ esrc, const int* __restrict__ edst,
    int* __restrict__ wpos, int* __restrict__ csr, int E, int sliceSize) {
  __shared__ __align__(16) unsigned short smem[4 * 128 * AST];
  int tid = threadIdx.x;
  int bx, by;
  if (FUSE) {
    int g = blockIdx.x / 9, r = blockIdx.x - g * 9;
    if (r < 5) {  // ---- scatter role ----
      int sid = g * 5 + r;
      if (sid < 1024) {
        int per = (E + 1023) >> 10;  // 782 @ E=800000; LDS use 2*per*4 B
        int b0 = sid * per;
        int cnt = min(per, E - b0);
        if (cnt > 0) {
          int* ss = (int*)smem;
          int* sd = ss + per;
          for (int i = tid; i < cnt; i += 256) {
            ss[i] = esrc[b0 + i];
            sd[i] = edst[b0 + i];
          }
          __syncthreads();
          for (int sl = 0; sl < 8; ++sl) {
            int lo = sl * sliceSize, hi = lo + sliceSize;
            for (int i = tid; i < cnt; i += 256) {
              int d = sd[i];
              if (d >= lo && d < hi) {
                int p = atomicAdd(&wpos[d], 1);
                csr[p] = ss[i];
              }
            }
          }
        }
      }
      return;
    }
    int gid = g * 4 + (r - 5);  // ---- gemm role ----
    int nbx = (nrows + 127) >> 7;
    if (gid >= nbx * 2) return;
    bx = gid >> 1;
    by = gid & 1;
  } else {
    bx = blockIdx.x;
    by = blockIdx.y;
  }

  unsigned short* sAh = smem;
  unsigned short* sAl = smem + 5120;
  unsigned short* sBh = smem + 10240;
  unsigned short* sBl = smem + 15360;

  int wave = tid >> 6, lane = tid & 63;
  int rowBase = bx * 128;
  int colBase = by * 128;
  int rowHalf = (wave >> 1) * 64;
  int colHalf = (wave & 1) * 64;
  int l15 = lane & 15, quad = lane >> 4;

  f32x4 acc[4][4];
#pragma unroll
  for (int m = 0; m < 4; ++m)
#pragma unroll
    for (int n = 0; n < 4; ++n) acc[m][n] = (f32x4){0.f, 0.f, 0.f, 0.f};

  for (int kc = 0; kc < 4; ++kc) {
    // stage A: 128 rows x 32 k (hi+lo); idx 0..511, 8 k-elems each
#pragma unroll
    for (int i = 0; i < 2; ++i) {
      int idx = tid + i * 256;
      int row = idx >> 2, seg = idx & 3;
      int gr = rowBase + row;
      if (MODE == IN_F32) {
        float4 v0 = make_float4(0.f, 0.f, 0.f, 0.f), v1 = v0;
        if (gr < nrows) {
          v0 = *(const float4*)&Af[(size_t)gr * 128 + kc * 32 + seg * 8];
          v1 = *(const float4*)&Af[(size_t)gr * 128 + kc * 32 + seg * 8 + 4];
        }
        ushort4 h0, l0, h1, l1;
        split4(v0, h0, l0);
        split4(v1, h1, l1);
        *(ushort4*)&sAh[row * AST + seg * 8] = h0;
        *(ushort4*)&sAh[row * AST + seg * 8 + 4] = h1;
        *(ushort4*)&sAl[row * AST + seg * 8] = l0;
        *(ushort4*)&sAl[row * AST + seg * 8 + 4] = l1;
      } else {  // IN_BFPAIR: pre-split bf16 hi/lo -> pure copies
        uint4 vh = make_uint4(0, 0, 0, 0), vl = vh;
        if (gr < nrows) {
          vh = *(const uint4*)&Ah[(size_t)gr * 128 + kc * 32 + seg * 8];
          vl = *(const uint4*)&Al[(size_t)gr * 128 + kc * 32 + seg * 8];
        }
        *(uint4*)&sAh[row * AST + seg * 8] = vh;
        *(uint4*)&sAl[row * AST + seg * 8] = vl;
      }
    }
    // stage B: 128 cols x 32 k (hi+lo); idx 0..511
#pragma unroll
    for (int i = 0; i < 2; ++i) {
      int idx = tid + i * 256;
      int col = idx >> 2, seg = idx & 3;
      *(uint4*)&sBh[col * AST + seg * 8] =
          *(const uint4*)&BTh[(size_t)(colBase + col) * 128 + kc * 32 + seg * 8];
      *(uint4*)&sBl[col * AST + seg * 8] =
          *(const uint4*)&BTl[(size_t)(colBase + col) * 128 + kc * 32 + seg * 8];
    }
    __syncthreads();

    bf16x8 afh[4], afl[4], bfh[4], bfl[4];
#pragma unroll
    for (int m = 0; m < 4; ++m) {
      int r = rowHalf + m * 16 + l15;
      afh[m] = *(const bf16x8*)&sAh[r * AST + quad * 8];
      afl[m] = *(const bf16x8*)&sAl[r * AST + quad * 8];
    }
#pragma unroll
    for (int n = 0; n < 4; ++n) {
      int cc = colHalf + n * 16 + l15;
      bfh[n] = *(const bf16x8*)&sBh[cc * AST + quad * 8];
      bfl[n] = *(const bf16x8*)&sBl[cc * AST + quad * 8];
    }
#pragma unroll
    for (int m = 0; m < 4; ++m)
#pragma unroll
      for (int n = 0; n < 4; ++n) {
        acc[m][n] = __builtin_amdgcn_mfma_f32_16x16x32_bf16(afh[m], bfh[n], acc[m][n], 0, 0, 0);
        acc[m][n] = __builtin_amdgcn_mfma_f32_16x16x32_bf16(afh[m], bfl[n], acc[m][n], 0, 0, 0);
        acc[m][n] = __builtin_amdgcn_mfma_f32_16x16x32_bf16(afl[m], bfh[n], acc[m][n], 0, 0, 0);
      }
    __syncthreads();
  }

  __half* __restrict__ C = (by == 0) ? Cl : Cr;
#pragma unroll
  for (int m = 0; m < 4; ++m)
#pragma unroll
    for (int r = 0; r < 4; ++r) {
      int grow = rowBase + rowHalf + m * 16 + quad * 4 + r;
      if (grow < nrows) {
#pragma unroll
        for (int n = 0; n < 4; ++n)
          C[(size_t)grow * 128 + colHalf + n * 16 + l15] = __float2half(acc[m][n][r]);
      }
    }
}

// ------------------------------ attention ----------------------------------
// One wave per node; 16 lanes/edge (8 ch/lane, one b128 fp16 load);
// 4 edge-slots/wave. Inner math: v_pk_add_f16 + v_fma_mix_f32 (abs folded).
// Outputs fp32 (layer 2) or bf16 hi/lo pair (layer 1 -> gemm2 input).
__global__ __launch_bounds__(256) void gat_attn(const __half* __restrict__ xl,
                                                const __half* __restrict__ xr,
                                                const int* __restrict__ row_start,
                                                const int* __restrict__ csr,
                                                const float* __restrict__ att,
                                                const float* __restrict__ bias,
                                                float* __restrict__ ofp,
                                                unsigned short* __restrict__ ohi,
                                                unsigned short* __restrict__ olo,
                                                int n_nodes) {
  int node = blockIdx.x * 4 + (threadIdx.x >> 6);
  if (node >= n_nodes) return;
  int lane = threadIdx.x & 63;
  int slot = lane >> 4;
  int l15 = lane & 15;
  int c0 = l15 * 8;

  // xr row kept packed fp16 (4 half2 words)
  unsigned hxr[4];
  {
    uint4 raw = *(const uint4*)&xr[(size_t)node * 128 + c0];
    const unsigned* q = (const unsigned*)&raw;
    hxr[0] = q[0]; hxr[1] = q[1]; hxr[2] = q[2]; hxr[3] = q[3];
  }
  // att row, pre-scaled: a06 = 0.6*log2e*a, a04 = 0.4*log2e*a
  float a06[8], a04[8];
  {
    float4 a0 = *(const float4*)&att[c0];
    float4 a1 = *(const float4*)&att[c0 + 4];
    float av[8] = {a0.x, a0.y, a0.z, a0.w, a1.x, a1.y, a1.z, a1.w};
    const float C06 = 0.6f * LOG2E, C04 = 0.4f * LOG2E;
#pragma unroll
    for (int k = 0; k < 8; ++k) { a06[k] = av[k] * C06; a04[k] = av[k] * C04; }
  }

  float acc[8];
#pragma unroll
  for (int k = 0; k < 8; ++k) acc[k] = 0.f;
  float lsum = 0.f;

#define EDGE_BODY(SRC, PVALID)                                                 \
  {                                                                            \
    uint4 raw = *(const uint4*)&xl[(size_t)(unsigned)(SRC)*128 + c0];          \
    const unsigned* xp = (const unsigned*)&raw;                                \
    float e0 = 0.f, e1 = 0.f;                                                  \
    _Pragma("unroll") for (int j = 0; j < 4; ++j) {                            \
      unsigned tw = pk_add(xp[j], hxr[j]);                                     \
      e0 = mixlo(a06[2 * j], tw, e0);                                          \
      e0 = mixlo_abs(a04[2 * j], tw, e0);                                      \
      e1 = mixhi(a06[2 * j + 1], tw, e1);                                      \
      e1 = mixhi_abs(a04[2 * j + 1], tw, e1);                                  \
    }                                                                          \
    float e = e0 + e1;                                                         \
    e += __shfl_xor(e, 1);                                                     \
    e += __shfl_xor(e, 2);                                                     \
    float p = (PVALID) ? __builtin_amdgcn_exp2f(e) : 0.f;                      \
    lsum += p;                                                                 \
    _Pragma("unroll") for (int j = 0; j < 4; ++j) {                            \
      acc[2 * j] = mixlo(p, xp[j], acc[2 * j]);                                \
      acc[2 * j + 1] = mixhi(p, xp[j], acc[2 * j + 1]);                        \
    }                                                                          \
  }

  int beg = row_start[node], end = row_start[node + 1];
  int deg = end - beg;  // includes self
  int fullEnd = beg + (deg & ~15);

  for (int base = beg; base < fullEnd; base += 16) {
    int b0 = base + 4 * slot;
    int s0 = csr[b0], s1 = csr[b0 + 1], s2 = csr[b0 + 2], s3 = csr[b0 + 3];
    EDGE_BODY(s0, true);
    EDGE_BODY(s1, true);
    EDGE_BODY(s2, true);
    EDGE_BODY(s3, true);
  }
  for (int base = fullEnd; base < end; base += 4) {  // csr padded by 16
    int idx = base + slot;
    int src = csr[idx];
    EDGE_BODY(src, idx < end);
  }
#undef EDGE_BODY

  // merge the 4 slots (same channels live in lanes with equal l15)
  lsum += __shfl_xor(lsum, 16);
  lsum += __shfl_xor(lsum, 32);
#pragma unroll
  for (int k = 0; k < 8; ++k) {
    acc[k] += __shfl_xor(acc[k], 16);
    acc[k] += __shfl_xor(acc[k], 32);
  }

  if (slot == 0) {
    float4 b0v = *(const float4*)&bias[c0];
    float4 b1v = *(const float4*)&bias[c0 + 4];
    float bv[8] = {b0v.x, b0v.y, b0v.z, b0v.w, b1v.x, b1v.y, b1v.z, b1v.w};
    float inv = 1.f / (lsum + 1e-16f);
    float o[8];
#pragma unroll
    for (int k = 0; k < 8; ++k) {
      float v = fmaf(acc[k], inv, bv[k]);
      o[k] = fmaf(0.495f, fabsf(v), 0.505f * v);  // leaky 0.01
    }
    if (ofp) {
      *(float4*)&ofp[(size_t)node * 128 + c0] = make_float4(o[0], o[1], o[2], o[3]);
      *(float4*)&ofp[(size_t)node * 128 + c0 + 4] = make_float4(o[4], o[5], o[6], o[7]);
    }
    if (ohi) {  // bf16 hi/lo pair for gemm2 (near-fp32 precision)
      ushort4 h0, h1, lo0, lo1;
      h0.x = f2bf(o[0]); lo0.x = f2bf(o[0] - bf2f(h0.x));
      h0.y = f2bf(o[1]); lo0.y = f2bf(o[1] - bf2f(h0.y));
      h0.z = f2bf(o[2]); lo0.z = f2bf(o[2] - bf2f(h0.z));
      h0.w = f2bf(o[3]); lo0.w = f2bf(o[3] - bf2f(h0.w));
      h1.x = f2bf(o[4]); lo1.x = f2bf(o[4] - bf2f(h1.x));
      h1.y = f2bf(o[5]); lo1.y = f2bf(o[5] - bf2f(h1.y));
      h1.z = f2bf(o[6]); lo1.z = f2bf(o[6] - bf2f(h1.z));
      h1.w = f2bf(o[7]); lo1.w = f2bf(o[7] - bf2f(h1.w));
      *(ushort4*)&ohi[(size_t)node * 128 + c0] = h0;
      *(ushort4*)&ohi[(size_t)node * 128 + c0 + 4] = h1;
      *(ushort4*)&olo[(size_t)node * 128 + c0] = lo0;
      *(ushort4*)&olo[(size_t)node * 128 + c0 + 4] = lo1;
    }
  }
}

// ------------------------------ classifier ---------------------------------
__global__ __launch_bounds__(256) void classifier_kernel(const float4* __restrict__ h4,
                                                         const float* __restrict__ Wc,
                                                         const float* __restrict__ bc,
                                                         float* __restrict__ logits,
                                                         int n) {
  __shared__ float sW[2048];
  __shared__ float sb[16];
  int t = threadIdx.x;
#pragma unroll
  for (int i = 0; i < 8; ++i) sW[t + i * 256] = Wc[t + i * 256];
  if (t < 16) sb[t] = bc[t];
  __syncthreads();
  int node = blockIdx.x * 256 + t;
  if (node >= n) return;
  float acc[16];
#pragma unroll
  for (int o = 0; o < 16; ++o) acc[o] = sb[o];
  for (int c4 = 0; c4 < 32; ++c4) {
    float4 hv = h4[(unsigned)node * 32 + c4];
    const float* w = &sW[c4 * 64];
#pragma unroll
    for (int o = 0; o < 16; ++o) {
      acc[o] = fmaf(hv.x, w[o], acc[o]);
      acc[o] = fmaf(hv.y, w[16 + o], acc[o]);
      acc[o] = fmaf(hv.z, w[32 + o], acc[o]);
      acc[o] = fmaf(hv.w, w[48 + o], acc[o]);
    }
  }
#pragma unroll
  for (int q = 0; q < 4; ++q)
    *(float4*)&logits[(size_t)node * 16 + q * 4] =
        make_float4(acc[q * 4], acc[q * 4 + 1], acc[q * 4 + 2], acc[q * 4 + 3]);
}

// ---------------------------------------------------------------------------

extern "C" void kernel_launch(void* const* d_in, const int* in_sizes, int n_in,
                              void* d_out, int out_size, void* d_ws, size_t ws_size,
                              hipStream_t stream) {
  const float* x    = (const float*)d_in[0];
  const int*   ei   = (const int*)d_in[1];
  const float* Wl1  = (const float*)d_in[3];
  const float* Wr1  = (const float*)d_in[4];
  const float* att1 = (const float*)d_in[5];
  const float* b1   = (const float*)d_in[6];
  const float* Wl2  = (const float*)d_in[7];
  const float* Wr2  = (const float*)d_in[8];
  const float* att2 = (const float*)d_in[9];
  const float* b2   = (const float*)d_in[10];
  const float* Wc   = (const float*)d_in[11];
  const float* bc   = (const float*)d_in[12];

  const int N = in_sizes[0] / 128;
  const int E = in_sizes[1] / 2;

  float* outp   = (float*)d_out;
  float* logits = outp;                   // N*16 fp32
  float* hout   = outp + (size_t)N * 16;  // N*128 fp32 region
  // h1 (bf16 hi/lo pair) staged in the hout region (overwritten by fp32 h2)
  unsigned short* h1h = (unsigned short*)hout;
  unsigned short* h1l = h1h + (size_t)N * 128;

  char* ws = (char*)d_ws;
  __half* xlbuf = (__half*)ws;                ws += (size_t)N * 128 * 2;
  __half* xrbuf = (__half*)ws;                ws += (size_t)N * 128 * 2;
  unsigned short* WT1h = (unsigned short*)ws; ws += 256 * 128 * 2;
  unsigned short* WT1l = (unsigned short*)ws; ws += 256 * 128 * 2;
  unsigned short* WT2h = (unsigned short*)ws; ws += 256 * 128 * 2;
  unsigned short* WT2l = (unsigned short*)ws; ws += 256 * 128 * 2;
  int* cnt       = (int*)ws;                  ws += (size_t)N * 4;
  int* row_start = (int*)ws;                  ws += (size_t)(N + 1) * 4;
  int* wpos      = (int*)ws;                  ws += (size_t)N * 4;
  int* bsum      = (int*)ws;                  ws += 256 * 4;
  int* csr       = (int*)ws;                  ws += (size_t)(E + N + 16) * 4;

  const int* esrc = ei;
  const int* edst = ei + E;

  int gN = (N + 255) / 256, gE = (E + 255) / 256;
  int gAttn = (N + 3) / 4;
  int sliceSize = (N + 7) / 8;

  int nbx = (N + 127) / 128;
  int nGemm = nbx * 2;
  int groups = (1024 + 4) / 5;                     // scatter blocks / 5
  int g2 = (nGemm + 3) / 4;                        // gemm blocks / 4
  if (g2 > groups) groups = g2;
  int gFused = groups * 9;

  // CSR build (self loops embedded: counts+1, csr[beg]=node)
  zero_i32<<<gN, 256, 0, stream>>>(cnt, N);
  convert_count<<<256 + gE, 256, 0, stream>>>(Wl1, Wr1, Wl2, Wr2,
                                              WT1h, WT1l, WT2h, WT2l,
                                              edst, cnt, E);
  scan_blk<<<gN, 256, 0, stream>>>(cnt, row_start, bsum, N);
  scan_bsum<<<1, 256, 0, stream>>>(bsum, gN, row_start, N);
  scan_add<<<gN, 256, 0, stream>>>(row_start, bsum, wpos, csr, N, E + N);

  // layer 1 GEMM (fp32 x, split inline) fused with CSR scatter
  gemm_mfma<IN_F32, 1><<<gFused, 256, 0, stream>>>(
      x, nullptr, nullptr, WT1h, WT1l, xlbuf, xrbuf, N,
      esrc, edst, wpos, csr, E, sliceSize);
  gat_attn<<<gAttn, 256, 0, stream>>>(xlbuf, xrbuf, row_start, csr, att1, b1,
                                      nullptr, h1h, h1l, N);

  // layer 2 (reads pre-split bf16 h1; staging is pure copies)
  gemm_mfma<IN_BFPAIR, 0><<<dim3(nbx, 2), 256, 0, stream>>>(
      nullptr, h1h, h1l, WT2h, WT2l, xlbuf, xrbuf, N,
      nullptr, nullptr, nullptr, nullptr, 0, 0);
  gat_attn<<<gAttn, 256, 0, stream>>>(xlbuf, xrbuf, row_start, csr, att2, b2,
                                      hout, nullptr, nullptr, N);

  // classifier
  classifier_kernel<<<(N + 255) / 256, 256, 0, stream>>>((const float4*)hout, Wc, bc,
                                                         logits, N);
}